// Round 3
// baseline (1250.765 us; speedup 1.0000x reference)
//
#include <hip/hip_runtime.h>
#include <math.h>

#define PI_F 3.14159274101257324f

// ---------------- workspace layout (float offsets) --------------------------
// Total: 411648 + 16777216 = 17,188,864 floats = ~65.6 MiB
#define OFF_C256   0u          // 65536
#define OFF_C128   65536u      // 16384
#define OFF_GATE   81920u      // 256
#define OFF_STATA  82176u      // 256
#define OFF_STATB  82432u      // 256
#define OFF_EMAA   82688u      // 256
#define OFF_EMAB   82944u      // 256
#define OFF_X2SUM  83200u      // 256
#define OFF_Q      83456u      // 256
#define OFF_R      83712u      // 32
#define OFF_P11    83744u      // 8 (pad to 83968)
#define OFF_XH     83968u      // 65536
#define OFF_XW     149504u     // 65536
#define OFF_SH     215040u     // 65536
#define OFF_SW     280576u     // 65536
#define OFF_PK     346112u     // 65536  (Pk = C64^T C64, symmetric 256x256)
#define OFF_BIG    411648u     // 16777216  (the single big ws slab)

// d_out doubles as a 16,777,216-float scratch slab ("DO") until the final
// kernel writes the real output into it.
//   LL = DO + 0        (4,194,304)
//   T1 = DO + 4194304  (4,194,304)
//   T2 = DO + 8388608  (4,194,304)
// Channel branch uses the whole DO as W1 = Pk@X (16,777,216) before spatial
// branch starts.

// ---------------- DCT matrices (replicate JAX fp32 expression order) --------
__global__ void k_dctmat(float* __restrict__ C256, float* __restrict__ C128) {
    int gid = blockIdx.x * 256 + threadIdx.x;
    if (gid < 65536) {
        int i = gid >> 8, j = gid & 255;
        float a = ((PI_F * ((float)j + 0.5f)) * (float)i) / 256.0f;
        float s = (i == 0) ? sqrtf(1.0f / 256.0f) : sqrtf(2.0f / 256.0f);
        C256[gid] = cosf(a) * s;
    } else if (gid < 65536 + 16384) {
        int g = gid - 65536;
        int i = g >> 7, j = g & 127;
        float a = ((PI_F * ((float)j + 0.5f)) * (float)i) / 128.0f;
        float s = (i == 0) ? sqrtf(1.0f / 128.0f) : sqrtf(2.0f / 128.0f);
        C128[g] = cosf(a) * s;
    }
}

// ---------------- Pk = C64^T @ C64 (256x256, K=64) --------------------------
// block i (256 blocks), thread j: Pk[i][j] = sum_k C[k][i]*C[k][j]
__global__ void k_pk(const float* __restrict__ C256, float* __restrict__ Pk) {
    int i = blockIdx.x, j = threadIdx.x;
    float s = 0.f;
#pragma unroll 8
    for (int k = 0; k < 64; k++)
        s = fmaf(C256[k * 256 + i], C256[k * 256 + j], s);
    Pk[i * 256 + j] = s;
}

// ---------------- LL subband:  LL[i,j] = mean of 2x2 quad -------------------
__global__ void k_ll(const float* __restrict__ X, float* __restrict__ LL) {
    int gid = blockIdx.x * 256 + threadIdx.x;        // 4,194,304
    int img = gid >> 14, rem = gid & 16383;
    int i = rem >> 7, j = rem & 127;
    const float* base = X + (size_t)img * 65536;
    float2 a = *(const float2*)(base + (2 * i) * 256 + 2 * j);
    float2 b = *(const float2*)(base + (2 * i + 1) * 256 + 2 * j);
    LL[gid] = (a.x + a.y + b.x + b.y) * 0.25f;
}

// ---------------- batched SGEMM: S1: Out[b]=C@In[b] ; !S1: Out[b]=In[b]@C^T -
// EPI: 0 none, 1 tanh-where + freq mask, 3 Out = Xref - acc
template <int N, bool S1, int EPI>
__global__ __launch_bounds__(256) void k_gemm(const float* __restrict__ Cm,
                                              const float* __restrict__ In,
                                              float* __restrict__ Out,
                                              const float* __restrict__ thr_ptr,
                                              const float* __restrict__ Xref) {
    __shared__ float As[16][68];
    __shared__ float Bs[16][68];
    const int tid = threadIdx.x;
    const int tx = tid & 15, ty = tid >> 4;
    const int j0 = blockIdx.x * 64, i0 = blockIdx.y * 64;
    const int b = blockIdx.z;
    const float* Inb = In + (size_t)b * N * N;

    float acc[4][4];
#pragma unroll
    for (int m = 0; m < 4; m++)
#pragma unroll
        for (int n = 0; n < 4; n++) acc[m][n] = 0.f;

    const int ra = tid >> 2;        // 0..63
    const int ka = (tid & 3) * 4;   // 0,4,8,12
    const int kb = tid >> 4;        // 0..15
    const int jb = (tid & 15) * 4;  // 0..60

    for (int k0 = 0; k0 < N; k0 += 16) {
        {   // A tile -> As[k][i]  (row-major along k, scatter-transpose)
            const float* pa = S1 ? (Cm + (size_t)(i0 + ra) * N + k0 + ka)
                                 : (Inb + (size_t)(i0 + ra) * N + k0 + ka);
            float4 v = *(const float4*)pa;
            As[ka + 0][ra] = v.x; As[ka + 1][ra] = v.y;
            As[ka + 2][ra] = v.z; As[ka + 3][ra] = v.w;
        }
        if (S1) {   // B tile (row-major [k][j]) -> Bs[k][j]
            const float* pb = Inb + (size_t)(k0 + kb) * N + j0 + jb;
            *(float4*)&Bs[kb][jb] = *(const float4*)pb;
        } else {    // B = C[j][k] -> Bs[k][j] scatter-transpose
            const float* pb = Cm + (size_t)(j0 + ra) * N + k0 + ka;
            float4 v = *(const float4*)pb;
            Bs[ka + 0][ra] = v.x; Bs[ka + 1][ra] = v.y;
            Bs[ka + 2][ra] = v.z; Bs[ka + 3][ra] = v.w;
        }
        __syncthreads();
#pragma unroll
        for (int k = 0; k < 16; k++) {
            float4 a = *(const float4*)&As[k][ty * 4];
            float4 bb = *(const float4*)&Bs[k][tx * 4];
            float av[4] = {a.x, a.y, a.z, a.w};
            float bv[4] = {bb.x, bb.y, bb.z, bb.w};
#pragma unroll
            for (int m = 0; m < 4; m++)
#pragma unroll
                for (int n = 0; n < 4; n++) acc[m][n] = fmaf(av[m], bv[n], acc[m][n]);
        }
        __syncthreads();
    }

    float thr = 0.f;
    if (EPI == 1) thr = thr_ptr[0];
#pragma unroll
    for (int m = 0; m < 4; m++) {
        int gi = i0 + ty * 4 + m;
        size_t rowoff = (size_t)b * N * N + (size_t)gi * N + j0 + tx * 4;
        float4 o;
        float* ov = (float*)&o;
        float4 xr;
        if (EPI == 3) xr = *(const float4*)&Xref[rowoff];
        const float* xrv = (const float*)&xr;
#pragma unroll
        for (int n = 0; n < 4; n++) {
            int gj = j0 + tx * 4 + n;
            float v = acc[m][n];
            if (EPI == 1) {
                if (fabsf(v) > thr) v = tanhf(v);
                if (gi < N / 4 && gj < N / 4) v = 0.f;
            } else if (EPI == 3) {
                v = xrv[n] - v;
            }
            ov[n] = v;
        }
        *(float4*)&Out[rowoff] = o;
    }
}

// ---------------- channel branch pooling + gate -----------------------------
__global__ __launch_bounds__(256) void k_pool_gate(const float* __restrict__ D,
                                                   const float* __restrict__ wc1,
                                                   const float* __restrict__ wc2,
                                                   float* __restrict__ gate) {
    __shared__ float sm[4], ss[4];
    const int img = blockIdx.x;
    const int c = img & 63;
    const int tid = threadIdx.x, lane = tid & 63, wid = tid >> 6;
    const float* base = D + (size_t)img * 65536;
    int r = tid >> 3, c4 = (tid & 7) * 4;
    float accM = 0.f, accA = 0.f;
    for (int t = 0; t < 64; t++) {
        int tr = t >> 3, tc = t & 7;
        const float* p = base + (size_t)(tr * 32 + r) * 256 + tc * 32 + c4;
        float4 v = *(const float4*)p;
        float mx = fmaxf(fmaxf(v.x, v.y), fmaxf(v.z, v.w));
        float s = v.x + v.y + v.z + v.w;
        for (int o = 32; o; o >>= 1) {
            mx = fmaxf(mx, __shfl_down(mx, o));
            s += __shfl_down(s, o);
        }
        if (lane == 0) { sm[wid] = mx; ss[wid] = s; }
        __syncthreads();
        if (tid == 0) {
            float m2 = fmaxf(fmaxf(sm[0], sm[1]), fmaxf(sm[2], sm[3]));
            float s2 = ss[0] + ss[1] + ss[2] + ss[3];
            float mean = s2 * (1.f / 1024.f);
            accM += 0.5f * m2 * (1.f + erff(m2 * 0.70710678118654752f));
            accA += 0.5f * mean * (1.f + erff(mean * 0.70710678118654752f));
        }
        __syncthreads();
    }
    if (tid == 0) {
        float c1 = wc1[c], c2 = wc2[c];
        float ch = fmaxf(c1 * accM, 0.f) + fmaxf(c1 * accA, 0.f);
        float g = fmaxf(c2 * ch, 0.f);
        gate[img] = 1.f / (1.f + expf(-g));
    }
}

// ---------------- z = x * (up2(d2) + gate) ----------------------------------
__global__ void k_zassm(const float* __restrict__ X, const float* __restrict__ D2,
                        const float* __restrict__ gate, float* __restrict__ Z) {
    int gid = blockIdx.x * 256 + threadIdx.x;  // 4,194,304 float4 units
    int img = gid >> 14, rem = gid & 16383;
    int h = rem >> 6, w4 = (rem & 63) * 4;
    float4 xv = *((const float4*)(X + (size_t)img * 65536 + (size_t)h * 256) + (rem & 63));
    float2 dd = *(const float2*)(D2 + (size_t)img * 16384 + (h >> 1) * 128 + (w4 >> 1));
    float g = gate[img];
    float4 o;
    o.x = xv.x * (dd.x + g); o.y = xv.y * (dd.x + g);
    o.z = xv.z * (dd.y + g); o.w = xv.w * (dd.y + g);
    *((float4*)(Z + (size_t)img * 65536 + (size_t)h * 256) + (rem & 63)) = o;
}

// ---------------- direct 3x3 conv (SAME), 8-out-ch group per block ----------
template <int CIN, bool RELU, bool DOSUM>
__global__ __launch_bounds__(256) void k_conv3(const float* __restrict__ In,
                                               const float* __restrict__ W,
                                               const float* __restrict__ Bias,
                                               float* __restrict__ Out,
                                               float* __restrict__ SumOut) {
    __shared__ float sIn[8][34][34];
    __shared__ float sW[8][8][9];
    __shared__ float rb[4];
    const int bz = blockIdx.z;
    int nImg, co0;
    if (CIN == 64) { nImg = bz >> 3; co0 = (bz & 7) * 8; }
    else           { nImg = bz;      co0 = 0; }
    const size_t inbase = (size_t)nImg * CIN * 65536;
    const size_t outbase = (size_t)nImg * ((CIN == 64) ? 64 : 8) * 65536;
    const int y0 = blockIdx.y * 32, x0 = blockIdx.x * 32;
    const int tid = threadIdx.x;
    const int tx = tid & 15, ty = tid >> 4;

    float acc[8][2][2];
#pragma unroll
    for (int a = 0; a < 8; a++)
#pragma unroll
        for (int d0 = 0; d0 < 2; d0++)
#pragma unroll
            for (int d1 = 0; d1 < 2; d1++) acc[a][d0][d1] = 0.f;

    for (int cc = 0; cc < CIN / 8; ++cc) {
        for (int idx = tid; idx < 8 * 34 * 34; idx += 256) {
            int ci = idx / 1156, rem = idx % 1156, iy = rem / 34, ix = rem % 34;
            int gy = y0 + iy - 1, gx = x0 + ix - 1;
            float v = 0.f;
            if (gy >= 0 && gy < 256 && gx >= 0 && gx < 256)
                v = In[inbase + (size_t)(cc * 8 + ci) * 65536 + (size_t)gy * 256 + gx];
            sIn[ci][iy][ix] = v;
        }
        for (int idx = tid; idx < 8 * 8 * 9; idx += 256) {
            int co = idx / 72, rem = idx % 72, ci = rem / 9, kk = rem % 9;
            sW[co][ci][kk] = W[((size_t)(co0 + co) * CIN + cc * 8 + ci) * 9 + kk];
        }
        __syncthreads();
#pragma unroll
        for (int ci = 0; ci < 8; ++ci) {
#pragma unroll
            for (int ky = 0; ky < 3; ky++) {
#pragma unroll
                for (int kx = 0; kx < 3; kx++) {
                    float wv[8];
#pragma unroll
                    for (int co = 0; co < 8; co++) wv[co] = sW[co][ci][ky * 3 + kx];
                    float v00 = sIn[ci][2 * ty + ky][2 * tx + kx];
                    float v01 = sIn[ci][2 * ty + ky][2 * tx + kx + 1];
                    float v10 = sIn[ci][2 * ty + ky + 1][2 * tx + kx];
                    float v11 = sIn[ci][2 * ty + ky + 1][2 * tx + kx + 1];
#pragma unroll
                    for (int co = 0; co < 8; co++) {
                        acc[co][0][0] = fmaf(wv[co], v00, acc[co][0][0]);
                        acc[co][0][1] = fmaf(wv[co], v01, acc[co][0][1]);
                        acc[co][1][0] = fmaf(wv[co], v10, acc[co][1][0]);
                        acc[co][1][1] = fmaf(wv[co], v11, acc[co][1][1]);
                    }
                }
            }
        }
        __syncthreads();
    }
#pragma unroll
    for (int co = 0; co < 8; co++) {
        float bsv = Bias[co0 + co];
#pragma unroll
        for (int dy = 0; dy < 2; dy++)
#pragma unroll
            for (int dx = 0; dx < 2; dx++) {
                float v = acc[co][dy][dx] + bsv;
                if (RELU) v = fmaxf(v, 0.f);
                Out[outbase + (size_t)(co0 + co) * 65536 +
                    (size_t)(y0 + 2 * ty + dy) * 256 + x0 + 2 * tx + dx] = v;
            }
    }
    if (DOSUM) {
        const int lane = tid & 63, wid = tid >> 6;
        for (int co = 0; co < 8; co++) {
            float s = acc[co][0][0] + acc[co][0][1] + acc[co][1][0] + acc[co][1][1] +
                      4.f * Bias[co0 + co];
            for (int o = 32; o; o >>= 1) s += __shfl_down(s, o);
            if (lane == 0) rb[wid] = s;
            __syncthreads();
            if (tid == 0) atomicAdd(&SumOut[nImg * 8 + co], rb[0] + rb[1] + rb[2] + rb[3]);
            __syncthreads();
        }
    }
}

// ---------------- per-(n,c) channel-norm stats ------------------------------
__global__ __launch_bounds__(256) void k_cnstats(const float* __restrict__ X,
                                                 const float* __restrict__ gw,
                                                 const float* __restrict__ gb,
                                                 float* __restrict__ A, float* __restrict__ B) {
    __shared__ float s1b[4], s2b[4];
    const int img = blockIdx.x;
    const float* base = X + (size_t)img * 65536;
    const int tid = threadIdx.x, lane = tid & 63, wid = tid >> 6;
    float s = 0.f, s2 = 0.f;
    for (int i = tid; i < 16384; i += 256) {
        float4 v = ((const float4*)base)[i];
        s += v.x + v.y + v.z + v.w;
        s2 += v.x * v.x + v.y * v.y + v.z * v.z + v.w * v.w;
    }
    for (int o = 32; o; o >>= 1) { s += __shfl_down(s, o); s2 += __shfl_down(s2, o); }
    if (lane == 0) { s1b[wid] = s; s2b[wid] = s2; }
    __syncthreads();
    if (tid == 0) {
        float S = s1b[0] + s1b[1] + s1b[2] + s1b[3];
        float S2 = s2b[0] + s2b[1] + s2b[2] + s2b[3];
        float mu = S * (1.f / 65536.f);
        float var = S2 * (1.f / 65536.f) - mu * mu;
        float al = gw[img & 63] * rsqrtf(var + 1e-5f);
        A[img] = al;
        B[img] = gb[img & 63] - mu * al;
    }
}

__global__ void k_cnapply(const float* __restrict__ X, const float* __restrict__ A,
                          const float* __restrict__ B, float* __restrict__ Y) {
    int gid = blockIdx.x * 256 + threadIdx.x;  // float4 units
    int img = gid >> 14;
    float a = A[img], b = B[img];
    float4 v = ((const float4*)X)[gid];
    float4 o = {fmaf(a, v.x, b), fmaf(a, v.y, b), fmaf(a, v.z, b), fmaf(a, v.w, b)};
    ((float4*)Y)[gid] = o;
}

// ---------------- EMA helpers -----------------------------------------------
__global__ void k_rowmean(const float* __restrict__ Y, float* __restrict__ XH) {
    int row = blockIdx.x * 4 + (threadIdx.x >> 6);   // 65536 rows
    int lane = threadIdx.x & 63;
    float4 v = ((const float4*)(Y + (size_t)row * 256))[lane];
    float s = v.x + v.y + v.z + v.w;
    for (int o = 32; o; o >>= 1) s += __shfl_down(s, o);
    if (lane == 0) XH[row] = s * (1.f / 256.f);
}

__global__ void k_colmean(const float* __restrict__ Y, float* __restrict__ XW) {
    int gid = blockIdx.x * 256 + threadIdx.x;  // 65536
    int img = gid >> 8, w = gid & 255;
    const float* p = Y + (size_t)img * 65536 + w;
    float s = 0.f;
    for (int h = 0; h < 256; h++) s += p[h * 256];
    XW[gid] = s * (1.f / 256.f);
}

__global__ void k_hw1x1(const float* __restrict__ XH, const float* __restrict__ XW,
                        const float* __restrict__ W1, const float* __restrict__ B1,
                        float* __restrict__ SH, float* __restrict__ SW) {
    int gid = blockIdx.x * 256 + threadIdx.x;  // 131072
    int half = gid >> 16;
    int rem = gid & 65535;
    int bg = rem >> 11, r2 = rem & 2047, co = r2 >> 8, p = r2 & 255;
    const float* src = (half ? XW : XH) + bg * 2048 + p;
    float s = B1[co];
#pragma unroll
    for (int ci = 0; ci < 8; ci++) s = fmaf(W1[co * 8 + ci], src[ci * 256], s);
    float sig = 1.f / (1.f + expf(-s));
    (half ? SW : SH)[bg * 2048 + co * 256 + p] = sig;
}

__global__ __launch_bounds__(256) void k_emastats(const float* __restrict__ Y,
                                                  const float* __restrict__ SH,
                                                  const float* __restrict__ SW,
                                                  const float* __restrict__ gnw,
                                                  const float* __restrict__ gnb,
                                                  float* __restrict__ A, float* __restrict__ B) {
    __shared__ float s1b[4], s2b[4];
    const int img = blockIdx.x;  // bg*8+ci
    const int bg = img >> 3, ci = img & 7;
    const float* base = Y + (size_t)img * 65536;
    const float* sh = SH + bg * 2048 + ci * 256;
    const float* sw = SW + bg * 2048 + ci * 256;
    const int tid = threadIdx.x, lane = tid & 63, wid = tid >> 6;
    float s = 0.f, s2 = 0.f;
    for (int i = tid; i < 65536; i += 256) {
        int h = i >> 8, w = i & 255;
        float t = base[i] * sh[h] * sw[w];
        s += t;
        s2 += t * t;
    }
    for (int o = 32; o; o >>= 1) { s += __shfl_down(s, o); s2 += __shfl_down(s2, o); }
    if (lane == 0) { s1b[wid] = s; s2b[wid] = s2; }
    __syncthreads();
    if (tid == 0) {
        float S = s1b[0] + s1b[1] + s1b[2] + s1b[3];
        float S2 = s2b[0] + s2b[1] + s2b[2] + s2b[3];
        float mu = S * (1.f / 65536.f);
        float var = S2 * (1.f / 65536.f) - mu * mu;
        float al = gnw[ci] * rsqrtf(var + 1e-5f);
        A[img] = al;
        B[img] = gnb[ci] - mu * al;
    }
}

__global__ void k_ema_smalls(const float* __restrict__ X2S, const float* __restrict__ EA,
                             const float* __restrict__ EB, const float* __restrict__ gnb,
                             float* __restrict__ Q, float* __restrict__ R,
                             float* __restrict__ P11) {
    int tid = threadIdx.x;  // 256 = 32 bg * 8 ci
    int ci = tid & 7;
    float m2 = X2S[tid] * (1.f / 65536.f);
    float mx = m2;
    mx = fmaxf(mx, __shfl_xor(mx, 1, 8));
    mx = fmaxf(mx, __shfl_xor(mx, 2, 8));
    mx = fmaxf(mx, __shfl_xor(mx, 4, 8));
    float e = expf(m2 - mx);
    float se = e;
    se += __shfl_xor(se, 1, 8); se += __shfl_xor(se, 2, 8); se += __shfl_xor(se, 4, 8);
    float x21 = e / se;
    Q[tid] = x21 * EA[tid];
    float rt = x21 * EB[tid];
    rt += __shfl_xor(rt, 1, 8); rt += __shfl_xor(rt, 2, 8); rt += __shfl_xor(rt, 4, 8);
    if (ci == 0) R[tid >> 3] = rt;
    float g = gnb[ci];
    float gm = g;
    gm = fmaxf(gm, __shfl_xor(gm, 1, 8));
    gm = fmaxf(gm, __shfl_xor(gm, 2, 8));
    gm = fmaxf(gm, __shfl_xor(gm, 4, 8));
    float ge = expf(g - gm);
    float gs = ge;
    gs += __shfl_xor(gs, 1, 8); gs += __shfl_xor(gs, 2, 8); gs += __shfl_xor(gs, 4, 8);
    if (tid < 8) P11[tid] = ge / gs;
}

// NOTE: X2 and Out intentionally NOT __restrict__ — they alias (both d_out).
// Each thread reads exactly the addresses it later writes; no cross-thread
// overlap, so per-thread program order (which the aliasing forces the
// compiler to preserve) is sufficient.
__global__ __launch_bounds__(256) void k_ema_final(const float* __restrict__ Y,
                                                   const float* X2,
                                                   const float* __restrict__ SH,
                                                   const float* __restrict__ SW,
                                                   const float* __restrict__ P11,
                                                   const float* __restrict__ Q,
                                                   const float* __restrict__ R,
                                                   float* Out) {
    int gid = blockIdx.x * 256 + threadIdx.x;  // 524288 = 32 bg * 16384 float4
    int bg = gid >> 14, rem = gid & 16383;
    int h = rem >> 6, w4i = rem & 63;
    float4 ys[8];
    float rv = R[bg];
    float4 acc = {rv, rv, rv, rv};
#pragma unroll
    for (int ci = 0; ci < 8; ci++) {
        size_t base = ((size_t)(bg * 8 + ci)) * 65536 + (size_t)h * 256;
        float4 yv = ((const float4*)(Y + base))[w4i];
        float4 xv = ((const float4*)(X2 + base))[w4i];
        ys[ci] = yv;
        float p = P11[ci], q = Q[bg * 8 + ci];
        float shv = SH[bg * 2048 + ci * 256 + h];
        float4 swv = ((const float4*)(SW + bg * 2048 + ci * 256))[w4i];
        float qs = q * shv;
        acc.x += p * xv.x + qs * yv.x * swv.x;
        acc.y += p * xv.y + qs * yv.y * swv.y;
        acc.z += p * xv.z + qs * yv.z * swv.z;
        acc.w += p * xv.w + qs * yv.w * swv.w;
    }
    float4 sg;
    sg.x = 1.f / (1.f + expf(-acc.x));
    sg.y = 1.f / (1.f + expf(-acc.y));
    sg.z = 1.f / (1.f + expf(-acc.z));
    sg.w = 1.f / (1.f + expf(-acc.w));
#pragma unroll
    for (int ci = 0; ci < 8; ci++) {
        float4 o = {ys[ci].x * sg.x, ys[ci].y * sg.y, ys[ci].z * sg.z, ys[ci].w * sg.w};
        ((float4*)(Out + ((size_t)(bg * 8 + ci)) * 65536 + (size_t)h * 256))[w4i] = o;
    }
}

// ---------------- launch ----------------------------------------------------
extern "C" void kernel_launch(void* const* d_in, const int* in_sizes, int n_in,
                              void* d_out, int out_size, void* d_ws, size_t ws_size,
                              hipStream_t stream) {
    (void)in_sizes; (void)n_in; (void)out_size; (void)ws_size;
    const float* x     = (const float*)d_in[0];
    const float* thr   = (const float*)d_in[1];
    const float* w_c1  = (const float*)d_in[2];
    const float* w_c2  = (const float*)d_in[3];
    const float* w_out = (const float*)d_in[4];
    const float* b_out = (const float*)d_in[5];
    const float* gn_w  = (const float*)d_in[6];
    const float* gn_b  = (const float*)d_in[7];
    const float* ew1   = (const float*)d_in[8];
    const float* eb1   = (const float*)d_in[9];
    const float* ew3   = (const float*)d_in[10];
    const float* eb3   = (const float*)d_in[11];
    const float* egw   = (const float*)d_in[12];
    const float* egb   = (const float*)d_in[13];

    float* ws   = (float*)d_ws;
    float* C256 = ws + OFF_C256;
    float* C128 = ws + OFF_C128;
    float* GATE = ws + OFF_GATE;
    float* SA_A = ws + OFF_STATA;
    float* SA_B = ws + OFF_STATB;
    float* EMAA = ws + OFF_EMAA;
    float* EMAB = ws + OFF_EMAB;
    float* X2S  = ws + OFF_X2SUM;
    float* Qb   = ws + OFF_Q;
    float* Rb   = ws + OFF_R;
    float* P11b = ws + OFF_P11;
    float* XH   = ws + OFF_XH;
    float* XW   = ws + OFF_XW;
    float* SHp  = ws + OFF_SH;
    float* SWp  = ws + OFF_SW;
    float* PK   = ws + OFF_PK;
    float* BIG  = ws + OFF_BIG;     // 16,777,216 floats

    float* DO  = (float*)d_out;     // 16,777,216 floats of scratch until the end
    float* LL  = DO;                // 4,194,304
    float* T1  = DO + 4194304;      // 4,194,304
    float* T2  = DO + 8388608;      // 4,194,304

    k_dctmat<<<320, 256, 0, stream>>>(C256, C128);
    k_pk<<<256, 256, 0, stream>>>(C256, PK);

    // ---- channel branch: dct_ = x - Pk@x@Pk  (2 big GEMMs) ----
    k_gemm<256, true, 0><<<dim3(4, 4, 256), 256, 0, stream>>>(PK, x, DO, nullptr, nullptr);
    k_gemm<256, false, 3><<<dim3(4, 4, 256), 256, 0, stream>>>(PK, DO, BIG, nullptr, x);
    k_pool_gate<<<256, 256, 0, stream>>>(BIG, w_c1, w_c2, GATE);      // dct_ in BIG -> gate

    // ---- spatial branch (lives entirely inside DO) ----
    k_ll<<<16384, 256, 0, stream>>>(x, LL);
    k_gemm<128, true, 0><<<dim3(2, 2, 256), 256, 0, stream>>>(C128, LL, T1, nullptr, nullptr);
    k_gemm<128, false, 1><<<dim3(2, 2, 256), 256, 0, stream>>>(C128, T1, T2, thr, nullptr);
    k_gemm<128, true, 0><<<dim3(2, 2, 256), 256, 0, stream>>>(C128, T2, T1, nullptr, nullptr);
    k_gemm<128, false, 0><<<dim3(2, 2, 256), 256, 0, stream>>>(C128, T1, T2, nullptr, nullptr);  // d2 in T2

    // ---- fuse: z = x * (up2(d2) + gate) -> BIG ----
    k_zassm<<<16384, 256, 0, stream>>>(x, T2, GATE, BIG);

    // ---- conv 64->64 + relu -> DO ; channel_norm -> y in BIG ----
    k_conv3<64, true, false><<<dim3(8, 8, 32), 256, 0, stream>>>(BIG, w_out, b_out, DO, nullptr);
    k_cnstats<<<256, 256, 0, stream>>>(DO, gn_w, gn_b, SA_A, SA_B);
    k_cnapply<<<16384, 256, 0, stream>>>(DO, SA_A, SA_B, BIG);

    // ---- EMA ----
    k_rowmean<<<16384, 256, 0, stream>>>(BIG, XH);
    k_colmean<<<256, 256, 0, stream>>>(BIG, XW);
    k_hw1x1<<<512, 256, 0, stream>>>(XH, XW, ew1, eb1, SHp, SWp);
    k_emastats<<<256, 256, 0, stream>>>(BIG, SHp, SWp, egw, egb, EMAA, EMAB);
    hipMemsetAsync(X2S, 0, 256 * sizeof(float), stream);
    k_conv3<8, false, true><<<dim3(8, 8, 32), 256, 0, stream>>>(BIG, ew3, eb3, DO, X2S);  // x2 in DO
    k_ema_smalls<<<1, 256, 0, stream>>>(X2S, EMAA, EMAB, egb, Qb, Rb, P11b);
    k_ema_final<<<2048, 256, 0, stream>>>(BIG, DO, SHp, SWp, P11b, Qb, Rb, (float*)d_out);
}

// Round 5
// 877.159 us; speedup vs baseline: 1.4259x; 1.4259x over previous
//
#include <hip/hip_runtime.h>
#include <math.h>

#define PI_F 3.14159274101257324f

// ---------------- workspace layout (float offsets) --------------------------
#define OFF_C256   0u          // 65536
#define OFF_C128   65536u      // 16384
#define OFF_GATE   81920u      // 256
#define OFF_STATA  82176u      // 256
#define OFF_STATB  82432u      // 256
#define OFF_EMAA   82688u      // 256
#define OFF_EMAB   82944u      // 256
#define OFF_X2SUM  83200u      // 256
#define OFF_Q      83456u      // 256
#define OFF_R      83712u      // 32
#define OFF_P11    83744u      // 8 (pad to 83968)
#define OFF_XH     83968u      // 65536
#define OFF_XW     149504u     // 65536
#define OFF_SH     215040u     // 65536
#define OFF_SW     280576u     // 65536
#define OFF_BIG    346112u     // 16777216  (the single big ws slab)
// total ws = 17,123,328 floats = ~65.3 MiB

// d_out ("DO", 16,777,216 floats) is scratch until the final kernel:
//   channel chain: U = DO+0 (4.19M), V = DO+4194304 (1.05M), W = DO+5242880 (4.19M)
//   spatial chain: LL = DO+0, T1 = DO+4194304, T2 = DO+8388608

// ---------------- DCT matrices (replicate JAX fp32 expression order) --------
__global__ void k_dctmat(float* __restrict__ C256, float* __restrict__ C128) {
    int gid = blockIdx.x * 256 + threadIdx.x;
    if (gid < 65536) {
        int i = gid >> 8, j = gid & 255;
        float a = ((PI_F * ((float)j + 0.5f)) * (float)i) / 256.0f;
        float s = (i == 0) ? sqrtf(1.0f / 256.0f) : sqrtf(2.0f / 256.0f);
        C256[gid] = cosf(a) * s;
    } else if (gid < 65536 + 16384) {
        int g = gid - 65536;
        int i = g >> 7, j = g & 127;
        float a = ((PI_F * ((float)j + 0.5f)) * (float)i) / 128.0f;
        float s = (i == 0) ? sqrtf(1.0f / 128.0f) : sqrtf(2.0f / 128.0f);
        C128[g] = cosf(a) * s;
    }
}

// ---------------- LL subband ------------------------------------------------
__global__ void k_ll(const float* __restrict__ X, float* __restrict__ LL) {
    int gid = blockIdx.x * 256 + threadIdx.x;        // 4,194,304
    int img = gid >> 14, rem = gid & 16383;
    int i = rem >> 7, j = rem & 127;
    const float* base = X + (size_t)img * 65536;
    float2 a = *(const float2*)(base + (2 * i) * 256 + 2 * j);
    float2 b = *(const float2*)(base + (2 * i + 1) * 256 + 2 * j);
    LL[gid] = (a.x + a.y + b.x + b.y) * 0.25f;
}

// ---------------- spatial-branch SGEMM (N=128) ------------------------------
// S1: Out[b]=C@In[b] ; !S1: Out[b]=In[b]@C^T.  EPI: 0 none, 1 tanh-where+mask
template <int N, bool S1, int EPI>
__global__ __launch_bounds__(256) void k_gemm(const float* __restrict__ Cm,
                                              const float* __restrict__ In,
                                              float* __restrict__ Out,
                                              const float* __restrict__ thr_ptr) {
    __shared__ float As[16][68];
    __shared__ float Bs[16][68];
    const int tid = threadIdx.x;
    const int tx = tid & 15, ty = tid >> 4;
    const int j0 = blockIdx.x * 64, i0 = blockIdx.y * 64;
    const int b = blockIdx.z;
    const float* Inb = In + (size_t)b * N * N;

    float acc[4][4];
#pragma unroll
    for (int m = 0; m < 4; m++)
#pragma unroll
        for (int n = 0; n < 4; n++) acc[m][n] = 0.f;

    const int ra = tid >> 2;
    const int ka = (tid & 3) * 4;
    const int kb = tid >> 4;
    const int jb = (tid & 15) * 4;

    for (int k0 = 0; k0 < N; k0 += 16) {
        {
            const float* pa = S1 ? (Cm + (size_t)(i0 + ra) * N + k0 + ka)
                                 : (Inb + (size_t)(i0 + ra) * N + k0 + ka);
            float4 v = *(const float4*)pa;
            As[ka + 0][ra] = v.x; As[ka + 1][ra] = v.y;
            As[ka + 2][ra] = v.z; As[ka + 3][ra] = v.w;
        }
        if (S1) {
            const float* pb = Inb + (size_t)(k0 + kb) * N + j0 + jb;
            *(float4*)&Bs[kb][jb] = *(const float4*)pb;
        } else {
            const float* pb = Cm + (size_t)(j0 + ra) * N + k0 + ka;
            float4 v = *(const float4*)pb;
            Bs[ka + 0][ra] = v.x; Bs[ka + 1][ra] = v.y;
            Bs[ka + 2][ra] = v.z; Bs[ka + 3][ra] = v.w;
        }
        __syncthreads();
#pragma unroll
        for (int k = 0; k < 16; k++) {
            float4 a = *(const float4*)&As[k][ty * 4];
            float4 bb = *(const float4*)&Bs[k][tx * 4];
            float av[4] = {a.x, a.y, a.z, a.w};
            float bv[4] = {bb.x, bb.y, bb.z, bb.w};
#pragma unroll
            for (int m = 0; m < 4; m++)
#pragma unroll
                for (int n = 0; n < 4; n++) acc[m][n] = fmaf(av[m], bv[n], acc[m][n]);
        }
        __syncthreads();
    }

    float thr = 0.f;
    if (EPI == 1) thr = thr_ptr[0];
#pragma unroll
    for (int m = 0; m < 4; m++) {
        int gi = i0 + ty * 4 + m;
        float4 o;
        float* ov = (float*)&o;
#pragma unroll
        for (int n = 0; n < 4; n++) {
            int gj = j0 + tx * 4 + n;
            float v = acc[m][n];
            if (EPI == 1) {
                if (fabsf(v) > thr) v = tanhf(v);
                if (gi < N / 4 && gj < N / 4) v = 0.f;
            }
            ov[n] = v;
        }
        *(float4*)&Out[(size_t)b * N * N + (size_t)gi * N + j0 + tx * 4] = o;
    }
}

// ---------------- generic batched GEMM (channel rank-64 chain) --------------
// A[i][k]: TA ? Ag[k*LDA+i] : Ag[i*LDA+k];  B[k][j]: TB ? Bg[j*LDB+k] : Bg[k*LDB+j]
// Out row-major N cols, batch stride M*N. EPI: 0 none, 3 Out = Xref - acc.
template <int M, int N, int K, int LDA, int LDB, bool TA, bool TB,
          long SA, long SB, int EPI>
__global__ __launch_bounds__(256) void k_bgemm(const float* __restrict__ A,
                                               const float* __restrict__ B,
                                               float* __restrict__ Out,
                                               const float* __restrict__ Xref) {
    __shared__ float As[16][68];
    __shared__ float Bs[16][68];
    const int tid = threadIdx.x;
    const int tx = tid & 15, ty = tid >> 4;
    const int j0 = blockIdx.x * 64, i0 = blockIdx.y * 64;
    const int b = blockIdx.z;
    const float* Ab = A + (size_t)b * (size_t)SA;
    const float* Bb = B + (size_t)b * (size_t)SB;

    float acc[4][4];
#pragma unroll
    for (int m = 0; m < 4; m++)
#pragma unroll
        for (int n = 0; n < 4; n++) acc[m][n] = 0.f;

    const int ra = tid >> 2;        // 0..63
    const int ka = (tid & 3) * 4;   // 0,4,8,12
    const int kb = tid >> 4;        // 0..15
    const int jb4 = (tid & 15) * 4; // 0..60

    for (int k0 = 0; k0 < K; k0 += 16) {
        if (!TA) {  // scatter-transpose rows of A
            float4 v = *(const float4*)(Ab + (size_t)(i0 + ra) * LDA + k0 + ka);
            As[ka + 0][ra] = v.x; As[ka + 1][ra] = v.y;
            As[ka + 2][ra] = v.z; As[ka + 3][ra] = v.w;
        } else {    // A^T stored row-major: direct copy
            *(float4*)&As[kb][jb4] =
                *(const float4*)(Ab + (size_t)(k0 + kb) * LDA + i0 + jb4);
        }
        if (!TB) {
            *(float4*)&Bs[kb][jb4] =
                *(const float4*)(Bb + (size_t)(k0 + kb) * LDB + j0 + jb4);
        } else {
            float4 v = *(const float4*)(Bb + (size_t)(j0 + ra) * LDB + k0 + ka);
            Bs[ka + 0][ra] = v.x; Bs[ka + 1][ra] = v.y;
            Bs[ka + 2][ra] = v.z; Bs[ka + 3][ra] = v.w;
        }
        __syncthreads();
#pragma unroll
        for (int k = 0; k < 16; k++) {
            float4 a = *(const float4*)&As[k][ty * 4];
            float4 bb = *(const float4*)&Bs[k][tx * 4];
            float av[4] = {a.x, a.y, a.z, a.w};
            float bv[4] = {bb.x, bb.y, bb.z, bb.w};
#pragma unroll
            for (int m = 0; m < 4; m++)
#pragma unroll
                for (int n = 0; n < 4; n++) acc[m][n] = fmaf(av[m], bv[n], acc[m][n]);
        }
        __syncthreads();
    }

#pragma unroll
    for (int m = 0; m < 4; m++) {
        size_t rowoff = (size_t)b * (size_t)M * N + (size_t)(i0 + ty * 4 + m) * N + j0 + tx * 4;
        float4 o;
        if (EPI == 3) {
            float4 xr = *(const float4*)&Xref[rowoff];
            o.x = xr.x - acc[m][0]; o.y = xr.y - acc[m][1];
            o.z = xr.z - acc[m][2]; o.w = xr.w - acc[m][3];
        } else {
            o.x = acc[m][0]; o.y = acc[m][1]; o.z = acc[m][2]; o.w = acc[m][3];
        }
        *(float4*)&Out[rowoff] = o;
    }
}

// ---------------- channel branch pooling + gate -----------------------------
__global__ __launch_bounds__(256) void k_pool_gate(const float* __restrict__ D,
                                                   const float* __restrict__ wc1,
                                                   const float* __restrict__ wc2,
                                                   float* __restrict__ gate) {
    __shared__ float sm[4], ss[4];
    const int img = blockIdx.x;
    const int c = img & 63;
    const int tid = threadIdx.x, lane = tid & 63, wid = tid >> 6;
    const float* base = D + (size_t)img * 65536;
    int r = tid >> 3, c4 = (tid & 7) * 4;
    float accM = 0.f, accA = 0.f;
    for (int t = 0; t < 64; t++) {
        int tr = t >> 3, tc = t & 7;
        const float* p = base + (size_t)(tr * 32 + r) * 256 + tc * 32 + c4;
        float4 v = *(const float4*)p;
        float mx = fmaxf(fmaxf(v.x, v.y), fmaxf(v.z, v.w));
        float s = v.x + v.y + v.z + v.w;
        for (int o = 32; o; o >>= 1) {
            mx = fmaxf(mx, __shfl_down(mx, o));
            s += __shfl_down(s, o);
        }
        if (lane == 0) { sm[wid] = mx; ss[wid] = s; }
        __syncthreads();
        if (tid == 0) {
            float m2 = fmaxf(fmaxf(sm[0], sm[1]), fmaxf(sm[2], sm[3]));
            float s2 = ss[0] + ss[1] + ss[2] + ss[3];
            float mean = s2 * (1.f / 1024.f);
            accM += 0.5f * m2 * (1.f + erff(m2 * 0.70710678118654752f));
            accA += 0.5f * mean * (1.f + erff(mean * 0.70710678118654752f));
        }
        __syncthreads();
    }
    if (tid == 0) {
        float c1 = wc1[c], c2 = wc2[c];
        float ch = fmaxf(c1 * accM, 0.f) + fmaxf(c1 * accA, 0.f);
        float g = fmaxf(c2 * ch, 0.f);
        gate[img] = 1.f / (1.f + expf(-g));
    }
}

// ---------------- z = x * (up2(d2) + gate) ----------------------------------
__global__ void k_zassm(const float* __restrict__ X, const float* __restrict__ D2,
                        const float* __restrict__ gate, float* __restrict__ Z) {
    int gid = blockIdx.x * 256 + threadIdx.x;  // 4,194,304 float4 units
    int img = gid >> 14, rem = gid & 16383;
    int h = rem >> 6, w4 = (rem & 63) * 4;
    float4 xv = *((const float4*)(X + (size_t)img * 65536 + (size_t)h * 256) + (rem & 63));
    float2 dd = *(const float2*)(D2 + (size_t)img * 16384 + (h >> 1) * 128 + (w4 >> 1));
    float g = gate[img];
    float4 o;
    o.x = xv.x * (dd.x + g); o.y = xv.y * (dd.x + g);
    o.z = xv.z * (dd.y + g); o.w = xv.w * (dd.y + g);
    *((float4*)(Z + (size_t)img * 65536 + (size_t)h * 256) + (rem & 63)) = o;
}

// ---------------- direct 3x3 conv v2: 1row x 4col x 8co per thread ----------
// Weights read straight from global with wave-uniform addresses -> s_load
// (SMEM pipe), LDS pipe only carries the input window.
template <int CIN, bool RELU, bool DOSUM>
__global__ __launch_bounds__(256, 4) void k_conv3(const float* __restrict__ In,
                                                  const float* __restrict__ W,
                                                  const float* __restrict__ Bias,
                                                  float* __restrict__ Out,
                                                  float* __restrict__ SumOut) {
    __shared__ float sIn[8][34][36];
    __shared__ float rb[4];
    const int bz = blockIdx.z;
    int nImg, co0;
    if (CIN == 64) { nImg = bz >> 3; co0 = (bz & 7) * 8; }
    else           { nImg = bz;      co0 = 0; }
    const size_t inbase  = (size_t)nImg * CIN * 65536;
    const size_t outbase = (size_t)nImg * ((CIN == 64) ? 64 : 8) * 65536;
    const int y0 = blockIdx.y * 32, x0 = blockIdx.x * 32;
    const int tid = threadIdx.x;
    const int row = tid >> 3;                 // 0..31
    const int tx  = tid & 7;                  // cols 4tx..4tx+3
    const int jl  = (tx == 0) ? 33 : 4 * tx - 1;   // left-window LDS col
    const int jr  = 4 * tx + 4;                    // right-window (tx=7 -> 32)

    float acc[8][4];
#pragma unroll
    for (int a = 0; a < 8; a++)
#pragma unroll
        for (int n = 0; n < 4; n++) acc[a][n] = 0.f;

    for (int cc = 0; cc < CIN / 8; ++cc) {
        if (cc) __syncthreads();
        // stage 8 ci x 34 rows; interior as aligned float4, halos scalar
        for (int t = tid; t < 272; t += 256) {
            int ci = t / 34, iy = t % 34;
            int gy = y0 + iy - 1;
            float* dst = &sIn[ci][iy][0];
            if (gy >= 0 && gy < 256) {
                const float* src = In + inbase + (size_t)(cc * 8 + ci) * 65536 + (size_t)gy * 256;
#pragma unroll
                for (int jb = 0; jb < 8; jb++)
                    *(float4*)(dst + 4 * jb) = *(const float4*)(src + x0 + 4 * jb);
                dst[32] = (x0 + 32 < 256) ? src[x0 + 32] : 0.f;
                dst[33] = (x0 - 1 >= 0)  ? src[x0 - 1]  : 0.f;
            } else {
                float4 z = {0.f, 0.f, 0.f, 0.f};
#pragma unroll
                for (int jb = 0; jb < 8; jb++) *(float4*)(dst + 4 * jb) = z;
                dst[32] = 0.f; dst[33] = 0.f;
            }
        }
        __syncthreads();

        const float* Wc = W + ((size_t)co0 * CIN + (size_t)cc * 8) * 9;
        for (int ci = 0; ci < 8; ++ci) {
            for (int ky = 0; ky < 3; ++ky) {
                const int iy = row + ky;
                float4 v = *(const float4*)&sIn[ci][iy][4 * tx];
                float win[6];
                win[0] = sIn[ci][iy][jl];
                win[1] = v.x; win[2] = v.y; win[3] = v.z; win[4] = v.w;
                win[5] = sIn[ci][iy][jr];
#pragma unroll
                for (int co = 0; co < 8; ++co) {
                    const float* wp = Wc + ((size_t)co * CIN + ci) * 9 + ky * 3;
                    float wa = wp[0], wb = wp[1], wc = wp[2];
#pragma unroll
                    for (int n = 0; n < 4; ++n)
                        acc[co][n] = fmaf(wa, win[n],
                                     fmaf(wb, win[n + 1],
                                     fmaf(wc, win[n + 2], acc[co][n])));
                }
            }
        }
    }

#pragma unroll
    for (int co = 0; co < 8; ++co) {
        float bsv = Bias[co0 + co];
        float4 o;
        o.x = acc[co][0] + bsv; o.y = acc[co][1] + bsv;
        o.z = acc[co][2] + bsv; o.w = acc[co][3] + bsv;
        if (RELU) {
            o.x = fmaxf(o.x, 0.f); o.y = fmaxf(o.y, 0.f);
            o.z = fmaxf(o.z, 0.f); o.w = fmaxf(o.w, 0.f);
        }
        *(float4*)&Out[outbase + (size_t)(co0 + co) * 65536 +
                       (size_t)(y0 + row) * 256 + x0 + 4 * tx] = o;
    }

    if (DOSUM) {
        const int lane = tid & 63, wid = tid >> 6;
        for (int co = 0; co < 8; co++) {
            float s = acc[co][0] + acc[co][1] + acc[co][2] + acc[co][3] +
                      4.f * Bias[co0 + co];
            for (int o = 32; o; o >>= 1) s += __shfl_down(s, o);
            if (lane == 0) rb[wid] = s;
            __syncthreads();
            if (tid == 0) atomicAdd(&SumOut[nImg * 8 + co], rb[0] + rb[1] + rb[2] + rb[3]);
            __syncthreads();
        }
    }
}

// ---------------- per-(n,c) channel-norm stats ------------------------------
__global__ __launch_bounds__(256) void k_cnstats(const float* __restrict__ X,
                                                 const float* __restrict__ gw,
                                                 const float* __restrict__ gb,
                                                 float* __restrict__ A, float* __restrict__ B) {
    __shared__ float s1b[4], s2b[4];
    const int img = blockIdx.x;
    const float* base = X + (size_t)img * 65536;
    const int tid = threadIdx.x, lane = tid & 63, wid = tid >> 6;
    float s = 0.f, s2 = 0.f;
    for (int i = tid; i < 16384; i += 256) {
        float4 v = ((const float4*)base)[i];
        s += v.x + v.y + v.z + v.w;
        s2 += v.x * v.x + v.y * v.y + v.z * v.z + v.w * v.w;
    }
    for (int o = 32; o; o >>= 1) { s += __shfl_down(s, o); s2 += __shfl_down(s2, o); }
    if (lane == 0) { s1b[wid] = s; s2b[wid] = s2; }
    __syncthreads();
    if (tid == 0) {
        float S = s1b[0] + s1b[1] + s1b[2] + s1b[3];
        float S2 = s2b[0] + s2b[1] + s2b[2] + s2b[3];
        float mu = S * (1.f / 65536.f);
        float var = S2 * (1.f / 65536.f) - mu * mu;
        float al = gw[img & 63] * rsqrtf(var + 1e-5f);
        A[img] = al;
        B[img] = gb[img & 63] - mu * al;
    }
}

__global__ void k_cnapply(const float* __restrict__ X, const float* __restrict__ A,
                          const float* __restrict__ B, float* __restrict__ Y) {
    int gid = blockIdx.x * 256 + threadIdx.x;
    int img = gid >> 14;
    float a = A[img], b = B[img];
    float4 v = ((const float4*)X)[gid];
    float4 o = {fmaf(a, v.x, b), fmaf(a, v.y, b), fmaf(a, v.z, b), fmaf(a, v.w, b)};
    ((float4*)Y)[gid] = o;
}

// ---------------- EMA helpers -----------------------------------------------
__global__ void k_rowmean(const float* __restrict__ Y, float* __restrict__ XH) {
    int row = blockIdx.x * 4 + (threadIdx.x >> 6);
    int lane = threadIdx.x & 63;
    float4 v = ((const float4*)(Y + (size_t)row * 256))[lane];
    float s = v.x + v.y + v.z + v.w;
    for (int o = 32; o; o >>= 1) s += __shfl_down(s, o);
    if (lane == 0) XH[row] = s * (1.f / 256.f);
}

__global__ void k_colmean(const float* __restrict__ Y, float* __restrict__ XW) {
    int gid = blockIdx.x * 256 + threadIdx.x;
    int img = gid >> 8, w = gid & 255;
    const float* p = Y + (size_t)img * 65536 + w;
    float s = 0.f;
    for (int h = 0; h < 256; h++) s += p[h * 256];
    XW[gid] = s * (1.f / 256.f);
}

__global__ void k_hw1x1(const float* __restrict__ XH, const float* __restrict__ XW,
                        const float* __restrict__ W1, const float* __restrict__ B1,
                        float* __restrict__ SH, float* __restrict__ SW) {
    int gid = blockIdx.x * 256 + threadIdx.x;
    int half = gid >> 16;
    int rem = gid & 65535;
    int bg = rem >> 11, r2 = rem & 2047, co = r2 >> 8, p = r2 & 255;
    const float* src = (half ? XW : XH) + bg * 2048 + p;
    float s = B1[co];
#pragma unroll
    for (int ci = 0; ci < 8; ci++) s = fmaf(W1[co * 8 + ci], src[ci * 256], s);
    float sig = 1.f / (1.f + expf(-s));
    (half ? SW : SH)[bg * 2048 + co * 256 + p] = sig;
}

__global__ __launch_bounds__(256) void k_emastats(const float* __restrict__ Y,
                                                  const float* __restrict__ SH,
                                                  const float* __restrict__ SW,
                                                  const float* __restrict__ gnw,
                                                  const float* __restrict__ gnb,
                                                  float* __restrict__ A, float* __restrict__ B) {
    __shared__ float s1b[4], s2b[4];
    const int img = blockIdx.x;
    const int bg = img >> 3, ci = img & 7;
    const float* base = Y + (size_t)img * 65536;
    const float* sh = SH + bg * 2048 + ci * 256;
    const float* sw = SW + bg * 2048 + ci * 256;
    const int tid = threadIdx.x, lane = tid & 63, wid = tid >> 6;
    float s = 0.f, s2 = 0.f;
    for (int i = tid; i < 65536; i += 256) {
        int h = i >> 8, w = i & 255;
        float t = base[i] * sh[h] * sw[w];
        s += t;
        s2 += t * t;
    }
    for (int o = 32; o; o >>= 1) { s += __shfl_down(s, o); s2 += __shfl_down(s2, o); }
    if (lane == 0) { s1b[wid] = s; s2b[wid] = s2; }
    __syncthreads();
    if (tid == 0) {
        float S = s1b[0] + s1b[1] + s1b[2] + s1b[3];
        float S2 = s2b[0] + s2b[1] + s2b[2] + s2b[3];
        float mu = S * (1.f / 65536.f);
        float var = S2 * (1.f / 65536.f) - mu * mu;
        float al = gnw[ci] * rsqrtf(var + 1e-5f);
        A[img] = al;
        B[img] = gnb[ci] - mu * al;
    }
}

__global__ void k_ema_smalls(const float* __restrict__ X2S, const float* __restrict__ EA,
                             const float* __restrict__ EB, const float* __restrict__ gnb,
                             float* __restrict__ Q, float* __restrict__ R,
                             float* __restrict__ P11) {
    int tid = threadIdx.x;
    int ci = tid & 7;
    float m2 = X2S[tid] * (1.f / 65536.f);
    float mx = m2;
    mx = fmaxf(mx, __shfl_xor(mx, 1, 8));
    mx = fmaxf(mx, __shfl_xor(mx, 2, 8));
    mx = fmaxf(mx, __shfl_xor(mx, 4, 8));
    float e = expf(m2 - mx);
    float se = e;
    se += __shfl_xor(se, 1, 8); se += __shfl_xor(se, 2, 8); se += __shfl_xor(se, 4, 8);
    float x21 = e / se;
    Q[tid] = x21 * EA[tid];
    float rt = x21 * EB[tid];
    rt += __shfl_xor(rt, 1, 8); rt += __shfl_xor(rt, 2, 8); rt += __shfl_xor(rt, 4, 8);
    if (ci == 0) R[tid >> 3] = rt;
    float g = gnb[ci];
    float gm = g;
    gm = fmaxf(gm, __shfl_xor(gm, 1, 8));
    gm = fmaxf(gm, __shfl_xor(gm, 2, 8));
    gm = fmaxf(gm, __shfl_xor(gm, 4, 8));
    float ge = expf(g - gm);
    float gs = ge;
    gs += __shfl_xor(gs, 1, 8); gs += __shfl_xor(gs, 2, 8); gs += __shfl_xor(gs, 4, 8);
    if (tid < 8) P11[tid] = ge / gs;
}

// NOTE: X2 and Out intentionally NOT __restrict__ — they alias (both d_out).
__global__ __launch_bounds__(256) void k_ema_final(const float* __restrict__ Y,
                                                   const float* X2,
                                                   const float* __restrict__ SH,
                                                   const float* __restrict__ SW,
                                                   const float* __restrict__ P11,
                                                   const float* __restrict__ Q,
                                                   const float* __restrict__ R,
                                                   float* Out) {
    int gid = blockIdx.x * 256 + threadIdx.x;
    int bg = gid >> 14, rem = gid & 16383;
    int h = rem >> 6, w4i = rem & 63;
    float4 ys[8];
    float rv = R[bg];
    float4 acc = {rv, rv, rv, rv};
#pragma unroll
    for (int ci = 0; ci < 8; ci++) {
        size_t base = ((size_t)(bg * 8 + ci)) * 65536 + (size_t)h * 256;
        float4 yv = ((const float4*)(Y + base))[w4i];
        float4 xv = ((const float4*)(X2 + base))[w4i];
        ys[ci] = yv;
        float p = P11[ci], q = Q[bg * 8 + ci];
        float shv = SH[bg * 2048 + ci * 256 + h];
        float4 swv = ((const float4*)(SW + bg * 2048 + ci * 256))[w4i];
        float qs = q * shv;
        acc.x += p * xv.x + qs * yv.x * swv.x;
        acc.y += p * xv.y + qs * yv.y * swv.y;
        acc.z += p * xv.z + qs * yv.z * swv.z;
        acc.w += p * xv.w + qs * yv.w * swv.w;
    }
    float4 sg;
    sg.x = 1.f / (1.f + expf(-acc.x));
    sg.y = 1.f / (1.f + expf(-acc.y));
    sg.z = 1.f / (1.f + expf(-acc.z));
    sg.w = 1.f / (1.f + expf(-acc.w));
#pragma unroll
    for (int ci = 0; ci < 8; ci++) {
        float4 o = {ys[ci].x * sg.x, ys[ci].y * sg.y, ys[ci].z * sg.z, ys[ci].w * sg.w};
        ((float4*)(Out + ((size_t)(bg * 8 + ci)) * 65536 + (size_t)h * 256))[w4i] = o;
    }
}

// ---------------- launch ----------------------------------------------------
extern "C" void kernel_launch(void* const* d_in, const int* in_sizes, int n_in,
                              void* d_out, int out_size, void* d_ws, size_t ws_size,
                              hipStream_t stream) {
    (void)in_sizes; (void)n_in; (void)out_size; (void)ws_size;
    const float* x     = (const float*)d_in[0];
    const float* thr   = (const float*)d_in[1];
    const float* w_c1  = (const float*)d_in[2];
    const float* w_c2  = (const float*)d_in[3];
    const float* w_out = (const float*)d_in[4];
    const float* b_out = (const float*)d_in[5];
    const float* gn_w  = (const float*)d_in[6];
    const float* gn_b  = (const float*)d_in[7];
    const float* ew1   = (const float*)d_in[8];
    const float* eb1   = (const float*)d_in[9];
    const float* ew3   = (const float*)d_in[10];
    const float* eb3   = (const float*)d_in[11];
    const float* egw   = (const float*)d_in[12];
    const float* egb   = (const float*)d_in[13];

    float* ws   = (float*)d_ws;
    float* C256 = ws + OFF_C256;   // rows 0..63 are E = C64
    float* C128 = ws + OFF_C128;
    float* GATE = ws + OFF_GATE;
    float* SA_A = ws + OFF_STATA;
    float* SA_B = ws + OFF_STATB;
    float* EMAA = ws + OFF_EMAA;
    float* EMAB = ws + OFF_EMAB;
    float* X2S  = ws + OFF_X2SUM;
    float* Qb   = ws + OFF_Q;
    float* Rb   = ws + OFF_R;
    float* P11b = ws + OFF_P11;
    float* XH   = ws + OFF_XH;
    float* XW   = ws + OFF_XW;
    float* SHp  = ws + OFF_SH;
    float* SWp  = ws + OFF_SW;
    float* BIG  = ws + OFF_BIG;

    float* DO  = (float*)d_out;
    float* Ubuf = DO;               // 64x256 x 256 imgs = 4,194,304
    float* Vbuf = DO + 4194304;     // 64x64  x 256 imgs = 1,048,576
    float* Wbuf = DO + 5242880;     // 256x64 x 256 imgs = 4,194,304
    float* LLb = DO;                // spatial chain reuses DO after channel done
    float* T1  = DO + 4194304;
    float* T2  = DO + 8388608;

    k_dctmat<<<320, 256, 0, stream>>>(C256, C128);

    // ---- channel branch: dct_ = x - E^T((E x)E^T)E  (rank-64) ----
    k_bgemm<64, 256, 256, 256, 256, false, false, 0, 65536, 0>
        <<<dim3(4, 1, 256), 256, 0, stream>>>(C256, x, Ubuf, nullptr);
    k_bgemm<64, 64, 256, 256, 256, false, true, 16384, 0, 0>
        <<<dim3(1, 1, 256), 256, 0, stream>>>(Ubuf, C256, Vbuf, nullptr);
    k_bgemm<256, 64, 64, 256, 64, true, false, 0, 4096, 0>
        <<<dim3(1, 4, 256), 256, 0, stream>>>(C256, Vbuf, Wbuf, nullptr);
    k_bgemm<256, 256, 64, 64, 256, false, false, 16384, 0, 3>
        <<<dim3(4, 4, 256), 256, 0, stream>>>(Wbuf, C256, BIG, x);
    k_pool_gate<<<256, 256, 0, stream>>>(BIG, w_c1, w_c2, GATE);

    // ---- spatial branch (inside DO) ----
    k_ll<<<16384, 256, 0, stream>>>(x, LLb);
    k_gemm<128, true, 0><<<dim3(2, 2, 256), 256, 0, stream>>>(C128, LLb, T1, nullptr);
    k_gemm<128, false, 1><<<dim3(2, 2, 256), 256, 0, stream>>>(C128, T1, T2, thr);
    k_gemm<128, true, 0><<<dim3(2, 2, 256), 256, 0, stream>>>(C128, T2, T1, nullptr);
    k_gemm<128, false, 0><<<dim3(2, 2, 256), 256, 0, stream>>>(C128, T1, T2, nullptr);

    // ---- fuse: z = x * (up2(d2) + gate) -> BIG ----
    k_zassm<<<16384, 256, 0, stream>>>(x, T2, GATE, BIG);

    // ---- conv 64->64 + relu -> DO ; channel_norm -> y in BIG ----
    k_conv3<64, true, false><<<dim3(8, 8, 32), 256, 0, stream>>>(BIG, w_out, b_out, DO, nullptr);
    k_cnstats<<<256, 256, 0, stream>>>(DO, gn_w, gn_b, SA_A, SA_B);
    k_cnapply<<<16384, 256, 0, stream>>>(DO, SA_A, SA_B, BIG);

    // ---- EMA ----
    k_rowmean<<<16384, 256, 0, stream>>>(BIG, XH);
    k_colmean<<<256, 256, 0, stream>>>(BIG, XW);
    k_hw1x1<<<512, 256, 0, stream>>>(XH, XW, ew1, eb1, SHp, SWp);
    k_emastats<<<256, 256, 0, stream>>>(BIG, SHp, SWp, egw, egb, EMAA, EMAB);
    hipMemsetAsync(X2S, 0, 256 * sizeof(float), stream);
    k_conv3<8, false, true><<<dim3(8, 8, 32), 256, 0, stream>>>(BIG, ew3, eb3, DO, X2S);
    k_ema_smalls<<<1, 256, 0, stream>>>(X2S, EMAA, EMAB, egb, Qb, Rb, P11b);
    k_ema_final<<<2048, 256, 0, stream>>>(BIG, DO, SHp, SWp, P11b, Qb, Rb, (float*)d_out);
}

// Round 7
// 830.695 us; speedup vs baseline: 1.5057x; 1.0559x over previous
//
#include <hip/hip_runtime.h>
#include <math.h>

#define PI_F 3.14159274101257324f

// ---------------- workspace layout (float offsets) --------------------------
#define OFF_C256   0u          // 65536
#define OFF_C128   65536u      // 16384
#define OFF_GATE   81920u      // 256
#define OFF_STATA  82176u      // 256
#define OFF_STATB  82432u      // 256
#define OFF_EMAA   82688u      // 256
#define OFF_EMAB   82944u      // 256
#define OFF_X2SUM  83200u      // 256
#define OFF_Q      83456u      // 256
#define OFF_R      83712u      // 32
#define OFF_P11    83744u      // 8 (pad to 83968)
#define OFF_XH     83968u      // 65536
#define OFF_XW     149504u     // 65536
#define OFF_SH     215040u     // 65536
#define OFF_SW     280576u     // 65536
#define OFF_BIG    346112u     // 16777216  (the single big ws slab)
// total ws = 17,123,328 floats = ~65.3 MiB

// d_out ("DO", 16,777,216 floats) is scratch until the final kernel:
//   channel chain: U = DO+0 (4.19M), V = DO+4194304 (1.05M), W = DO+5242880 (4.19M)
//   spatial chain: LL = DO+0, T1 = DO+4194304, T2 = DO+8388608

// ---------------- DCT matrices (replicate JAX fp32 expression order) --------
__global__ void k_dctmat(float* __restrict__ C256, float* __restrict__ C128) {
    int gid = blockIdx.x * 256 + threadIdx.x;
    if (gid < 65536) {
        int i = gid >> 8, j = gid & 255;
        float a = ((PI_F * ((float)j + 0.5f)) * (float)i) / 256.0f;
        float s = (i == 0) ? sqrtf(1.0f / 256.0f) : sqrtf(2.0f / 256.0f);
        C256[gid] = cosf(a) * s;
    } else if (gid < 65536 + 16384) {
        int g = gid - 65536;
        int i = g >> 7, j = g & 127;
        float a = ((PI_F * ((float)j + 0.5f)) * (float)i) / 128.0f;
        float s = (i == 0) ? sqrtf(1.0f / 128.0f) : sqrtf(2.0f / 128.0f);
        C128[g] = cosf(a) * s;
    }
}

// ---------------- LL subband ------------------------------------------------
__global__ void k_ll(const float* __restrict__ X, float* __restrict__ LL) {
    int gid = blockIdx.x * 256 + threadIdx.x;        // 4,194,304
    int img = gid >> 14, rem = gid & 16383;
    int i = rem >> 7, j = rem & 127;
    const float* base = X + (size_t)img * 65536;
    float2 a = *(const float2*)(base + (2 * i) * 256 + 2 * j);
    float2 b = *(const float2*)(base + (2 * i + 1) * 256 + 2 * j);
    LL[gid] = (a.x + a.y + b.x + b.y) * 0.25f;
}

// ---------------- spatial-branch SGEMM (N=128) ------------------------------
// S1: Out[b]=C@In[b] ; !S1: Out[b]=In[b]@C^T.  EPI: 0 none, 1 tanh-where+mask
template <int N, bool S1, int EPI>
__global__ __launch_bounds__(256) void k_gemm(const float* __restrict__ Cm,
                                              const float* __restrict__ In,
                                              float* __restrict__ Out,
                                              const float* __restrict__ thr_ptr) {
    __shared__ float As[16][68];
    __shared__ float Bs[16][68];
    const int tid = threadIdx.x;
    const int tx = tid & 15, ty = tid >> 4;
    const int j0 = blockIdx.x * 64, i0 = blockIdx.y * 64;
    const int b = blockIdx.z;
    const float* Inb = In + (size_t)b * N * N;

    float acc[4][4];
#pragma unroll
    for (int m = 0; m < 4; m++)
#pragma unroll
        for (int n = 0; n < 4; n++) acc[m][n] = 0.f;

    const int ra = tid >> 2;
    const int ka = (tid & 3) * 4;
    const int kb = tid >> 4;
    const int jb = (tid & 15) * 4;

    for (int k0 = 0; k0 < N; k0 += 16) {
        {
            const float* pa = S1 ? (Cm + (size_t)(i0 + ra) * N + k0 + ka)
                                 : (Inb + (size_t)(i0 + ra) * N + k0 + ka);
            float4 v = *(const float4*)pa;
            As[ka + 0][ra] = v.x; As[ka + 1][ra] = v.y;
            As[ka + 2][ra] = v.z; As[ka + 3][ra] = v.w;
        }
        if (S1) {
            const float* pb = Inb + (size_t)(k0 + kb) * N + j0 + jb;
            *(float4*)&Bs[kb][jb] = *(const float4*)pb;
        } else {
            const float* pb = Cm + (size_t)(j0 + ra) * N + k0 + ka;
            float4 v = *(const float4*)pb;
            Bs[ka + 0][ra] = v.x; Bs[ka + 1][ra] = v.y;
            Bs[ka + 2][ra] = v.z; Bs[ka + 3][ra] = v.w;
        }
        __syncthreads();
#pragma unroll
        for (int k = 0; k < 16; k++) {
            float4 a = *(const float4*)&As[k][ty * 4];
            float4 bb = *(const float4*)&Bs[k][tx * 4];
            float av[4] = {a.x, a.y, a.z, a.w};
            float bv[4] = {bb.x, bb.y, bb.z, bb.w};
#pragma unroll
            for (int m = 0; m < 4; m++)
#pragma unroll
                for (int n = 0; n < 4; n++) acc[m][n] = fmaf(av[m], bv[n], acc[m][n]);
        }
        __syncthreads();
    }

    float thr = 0.f;
    if (EPI == 1) thr = thr_ptr[0];
#pragma unroll
    for (int m = 0; m < 4; m++) {
        int gi = i0 + ty * 4 + m;
        float4 o;
        float* ov = (float*)&o;
#pragma unroll
        for (int n = 0; n < 4; n++) {
            int gj = j0 + tx * 4 + n;
            float v = acc[m][n];
            if (EPI == 1) {
                if (fabsf(v) > thr) v = tanhf(v);
                if (gi < N / 4 && gj < N / 4) v = 0.f;
            }
            ov[n] = v;
        }
        *(float4*)&Out[(size_t)b * N * N + (size_t)gi * N + j0 + tx * 4] = o;
    }
}

// ---------------- generic batched GEMM (channel rank-64 chain) --------------
// A[i][k]: TA ? Ag[k*LDA+i] : Ag[i*LDA+k];  B[k][j]: TB ? Bg[j*LDB+k] : Bg[k*LDB+j]
// Out row-major N cols, batch stride M*N. EPI: 0 none, 3 Out = Xref - acc.
template <int M, int N, int K, int LDA, int LDB, bool TA, bool TB,
          long SA, long SB, int EPI>
__global__ __launch_bounds__(256) void k_bgemm(const float* __restrict__ A,
                                               const float* __restrict__ B,
                                               float* __restrict__ Out,
                                               const float* __restrict__ Xref) {
    __shared__ float As[16][68];
    __shared__ float Bs[16][68];
    const int tid = threadIdx.x;
    const int tx = tid & 15, ty = tid >> 4;
    const int j0 = blockIdx.x * 64, i0 = blockIdx.y * 64;
    const int b = blockIdx.z;
    const float* Ab = A + (size_t)b * (size_t)SA;
    const float* Bb = B + (size_t)b * (size_t)SB;

    float acc[4][4];
#pragma unroll
    for (int m = 0; m < 4; m++)
#pragma unroll
        for (int n = 0; n < 4; n++) acc[m][n] = 0.f;

    const int ra = tid >> 2;        // 0..63
    const int ka = (tid & 3) * 4;   // 0,4,8,12
    const int kb = tid >> 4;        // 0..15
    const int jb4 = (tid & 15) * 4; // 0..60

    for (int k0 = 0; k0 < K; k0 += 16) {
        if (!TA) {  // scatter-transpose rows of A
            float4 v = *(const float4*)(Ab + (size_t)(i0 + ra) * LDA + k0 + ka);
            As[ka + 0][ra] = v.x; As[ka + 1][ra] = v.y;
            As[ka + 2][ra] = v.z; As[ka + 3][ra] = v.w;
        } else {    // A^T stored row-major: direct copy
            *(float4*)&As[kb][jb4] =
                *(const float4*)(Ab + (size_t)(k0 + kb) * LDA + i0 + jb4);
        }
        if (!TB) {
            *(float4*)&Bs[kb][jb4] =
                *(const float4*)(Bb + (size_t)(k0 + kb) * LDB + j0 + jb4);
        } else {
            float4 v = *(const float4*)(Bb + (size_t)(j0 + ra) * LDB + k0 + ka);
            Bs[ka + 0][ra] = v.x; Bs[ka + 1][ra] = v.y;
            Bs[ka + 2][ra] = v.z; Bs[ka + 3][ra] = v.w;
        }
        __syncthreads();
#pragma unroll
        for (int k = 0; k < 16; k++) {
            float4 a = *(const float4*)&As[k][ty * 4];
            float4 bb = *(const float4*)&Bs[k][tx * 4];
            float av[4] = {a.x, a.y, a.z, a.w};
            float bv[4] = {bb.x, bb.y, bb.z, bb.w};
#pragma unroll
            for (int m = 0; m < 4; m++)
#pragma unroll
                for (int n = 0; n < 4; n++) acc[m][n] = fmaf(av[m], bv[n], acc[m][n]);
        }
        __syncthreads();
    }

#pragma unroll
    for (int m = 0; m < 4; m++) {
        size_t rowoff = (size_t)b * (size_t)M * N + (size_t)(i0 + ty * 4 + m) * N + j0 + tx * 4;
        float4 o;
        if (EPI == 3) {
            float4 xr = *(const float4*)&Xref[rowoff];
            o.x = xr.x - acc[m][0]; o.y = xr.y - acc[m][1];
            o.z = xr.z - acc[m][2]; o.w = xr.w - acc[m][3];
        } else {
            o.x = acc[m][0]; o.y = acc[m][1]; o.z = acc[m][2]; o.w = acc[m][3];
        }
        *(float4*)&Out[rowoff] = o;
    }
}

// ---------------- channel branch pooling + gate (parallel tiles) ------------
// 64 tiles of 32x32; one tile per 4-lane group; 1 barrier total.
__global__ __launch_bounds__(256) void k_pool_gate(const float* __restrict__ D,
                                                   const float* __restrict__ wc1,
                                                   const float* __restrict__ wc2,
                                                   float* __restrict__ gate) {
    __shared__ float redM[4], redA[4];
    const int img = blockIdx.x;
    const int c = img & 63;
    const int tid = threadIdx.x, lane = tid & 63, wid = tid >> 6;
    const int t = tid >> 2;          // tile 0..63
    const int sub = tid & 3;         // quarter-tile (8 rows)
    const int tr = t >> 3, tc = t & 7;
    const float* base = D + (size_t)img * 65536 + (size_t)(tr * 32 + sub * 8) * 256 + tc * 32;

    float mx = -3.4e38f, sum = 0.f;
#pragma unroll
    for (int r = 0; r < 8; r++) {
#pragma unroll
        for (int c4 = 0; c4 < 8; c4++) {
            float4 v = *(const float4*)(base + (size_t)r * 256 + 4 * c4);
            mx = fmaxf(mx, fmaxf(fmaxf(v.x, v.y), fmaxf(v.z, v.w)));
            sum += v.x + v.y + v.z + v.w;
        }
    }
    // combine the 4 lanes of this tile
    mx = fmaxf(mx, __shfl_xor(mx, 1)); sum += __shfl_xor(sum, 1);
    mx = fmaxf(mx, __shfl_xor(mx, 2)); sum += __shfl_xor(sum, 2);

    float gM = 0.f, gA = 0.f;
    if (sub == 0) {
        float mean = sum * (1.f / 1024.f);
        gM = 0.5f * mx * (1.f + erff(mx * 0.70710678118654752f));
        gA = 0.5f * mean * (1.f + erff(mean * 0.70710678118654752f));
    }
    for (int o = 32; o; o >>= 1) { gM += __shfl_down(gM, o); gA += __shfl_down(gA, o); }
    if (lane == 0) { redM[wid] = gM; redA[wid] = gA; }
    __syncthreads();
    if (tid == 0) {
        float accM = redM[0] + redM[1] + redM[2] + redM[3];
        float accA = redA[0] + redA[1] + redA[2] + redA[3];
        float c1 = wc1[c], c2 = wc2[c];
        float ch = fmaxf(c1 * accM, 0.f) + fmaxf(c1 * accA, 0.f);
        float g = fmaxf(c2 * ch, 0.f);
        gate[img] = 1.f / (1.f + expf(-g));
    }
}

// ---------------- z = x * (up2(d2) + gate) ----------------------------------
__global__ void k_zassm(const float* __restrict__ X, const float* __restrict__ D2,
                        const float* __restrict__ gate, float* __restrict__ Z) {
    int gid = blockIdx.x * 256 + threadIdx.x;  // 4,194,304 float4 units
    int img = gid >> 14, rem = gid & 16383;
    int h = rem >> 6, w4 = (rem & 63) * 4;
    float4 xv = *((const float4*)(X + (size_t)img * 65536 + (size_t)h * 256) + (rem & 63));
    float2 dd = *(const float2*)(D2 + (size_t)img * 16384 + (h >> 1) * 128 + (w4 >> 1));
    float g = gate[img];
    float4 o;
    o.x = xv.x * (dd.x + g); o.y = xv.y * (dd.x + g);
    o.z = xv.z * (dd.y + g); o.w = xv.w * (dd.y + g);
    *((float4*)(Z + (size_t)img * 65536 + (size_t)h * 256) + (rem & 63)) = o;
}

// ---------------- direct 3x3 conv v3: stride-37 LDS (conflict-free) ---------
// Row stride 37 (coprime to 32 banks): bank = (5*iy + col) % 32 -> no two
// half-wave lanes collide for reads or staged writes. Scalar ds ops.
// Weights from global with wave-uniform addresses -> scalar s_load pipe.
template <int CIN, bool RELU, bool DOSUM>
__global__ __launch_bounds__(256, 4) void k_conv3(const float* __restrict__ In,
                                                  const float* __restrict__ W,
                                                  const float* __restrict__ Bias,
                                                  float* __restrict__ Out,
                                                  float* __restrict__ SumOut) {
    __shared__ float sIn[8][34][37];
    __shared__ float rb[4];
    const int bz = blockIdx.z;
    int nImg, co0;
    if (CIN == 64) { nImg = bz >> 3; co0 = (bz & 7) * 8; }
    else           { nImg = bz;      co0 = 0; }
    const size_t inbase  = (size_t)nImg * CIN * 65536;
    const size_t outbase = (size_t)nImg * ((CIN == 64) ? 64 : 8) * 65536;
    const int y0 = blockIdx.y * 32, x0 = blockIdx.x * 32;
    const int tid = threadIdx.x;
    const int row = tid >> 3;                 // 0..31
    const int tx  = tid & 7;                  // cols 4tx..4tx+3
    const int cL  = (tx == 0) ? 33 : 4 * tx - 1;   // left-halo col in LDS

    float acc[8][4];
#pragma unroll
    for (int a = 0; a < 8; a++)
#pragma unroll
        for (int n = 0; n < 4; n++) acc[a][n] = 0.f;

    for (int cc = 0; cc < CIN / 8; ++cc) {
        if (cc) __syncthreads();
        // stage 8 ci x 34 rows: float4 global loads, scalar LDS writes
        for (int t = tid; t < 272; t += 256) {
            int ci = t / 34, iy = t % 34;
            int gy = y0 + iy - 1;
            float* dst = &sIn[ci][iy][0];
            if (gy >= 0 && gy < 256) {
                const float* src = In + inbase + (size_t)(cc * 8 + ci) * 65536 + (size_t)gy * 256;
#pragma unroll
                for (int jb = 0; jb < 8; jb++) {
                    float4 v = *(const float4*)(src + x0 + 4 * jb);
                    dst[4 * jb + 0] = v.x; dst[4 * jb + 1] = v.y;
                    dst[4 * jb + 2] = v.z; dst[4 * jb + 3] = v.w;
                }
                dst[32] = (x0 + 32 < 256) ? src[x0 + 32] : 0.f;
                dst[33] = (x0 - 1 >= 0)  ? src[x0 - 1]  : 0.f;
            } else {
#pragma unroll
                for (int j = 0; j < 34; j++) dst[j] = 0.f;
            }
        }
        __syncthreads();

        const float* Wc = W + ((size_t)co0 * CIN + (size_t)cc * 8) * 9;
        for (int ci = 0; ci < 8; ++ci) {
            for (int ky = 0; ky < 3; ++ky) {
                const int iy = row + ky;
                const float* rowp = &sIn[ci][iy][0];
                float win[6];
                win[0] = rowp[cL];
                win[1] = rowp[4 * tx + 0];
                win[2] = rowp[4 * tx + 1];
                win[3] = rowp[4 * tx + 2];
                win[4] = rowp[4 * tx + 3];
                win[5] = rowp[4 * tx + 4];   // tx=7 -> col 32 (right halo)
#pragma unroll
                for (int co = 0; co < 8; ++co) {
                    const float* wp = Wc + ((size_t)co * CIN + ci) * 9 + ky * 3;
                    float wa = wp[0], wb = wp[1], wc = wp[2];
#pragma unroll
                    for (int n = 0; n < 4; ++n)
                        acc[co][n] = fmaf(wa, win[n],
                                     fmaf(wb, win[n + 1],
                                     fmaf(wc, win[n + 2], acc[co][n])));
                }
            }
        }
    }

#pragma unroll
    for (int co = 0; co < 8; ++co) {
        float bsv = Bias[co0 + co];
        float4 o;
        o.x = acc[co][0] + bsv; o.y = acc[co][1] + bsv;
        o.z = acc[co][2] + bsv; o.w = acc[co][3] + bsv;
        if (RELU) {
            o.x = fmaxf(o.x, 0.f); o.y = fmaxf(o.y, 0.f);
            o.z = fmaxf(o.z, 0.f); o.w = fmaxf(o.w, 0.f);
        }
        *(float4*)&Out[outbase + (size_t)(co0 + co) * 65536 +
                       (size_t)(y0 + row) * 256 + x0 + 4 * tx] = o;
    }

    if (DOSUM) {
        const int lane = tid & 63, wid = tid >> 6;
        for (int co = 0; co < 8; co++) {
            float s = acc[co][0] + acc[co][1] + acc[co][2] + acc[co][3] +
                      4.f * Bias[co0 + co];
            for (int o = 32; o; o >>= 1) s += __shfl_down(s, o);
            if (lane == 0) rb[wid] = s;
            __syncthreads();
            if (tid == 0) atomicAdd(&SumOut[nImg * 8 + co], rb[0] + rb[1] + rb[2] + rb[3]);
            __syncthreads();
        }
    }
}

// ---------------- per-(n,c) channel-norm stats ------------------------------
__global__ __launch_bounds__(256) void k_cnstats(const float* __restrict__ X,
                                                 const float* __restrict__ gw,
                                                 const float* __restrict__ gb,
                                                 float* __restrict__ A, float* __restrict__ B) {
    __shared__ float s1b[4], s2b[4];
    const int img = blockIdx.x;
    const float* base = X + (size_t)img * 65536;
    const int tid = threadIdx.x, lane = tid & 63, wid = tid >> 6;
    float s = 0.f, s2 = 0.f;
    for (int i = tid; i < 16384; i += 256) {
        float4 v = ((const float4*)base)[i];
        s += v.x + v.y + v.z + v.w;
        s2 += v.x * v.x + v.y * v.y + v.z * v.z + v.w * v.w;
    }
    for (int o = 32; o; o >>= 1) { s += __shfl_down(s, o); s2 += __shfl_down(s2, o); }
    if (lane == 0) { s1b[wid] = s; s2b[wid] = s2; }
    __syncthreads();
    if (tid == 0) {
        float S = s1b[0] + s1b[1] + s1b[2] + s1b[3];
        float S2 = s2b[0] + s2b[1] + s2b[2] + s2b[3];
        float mu = S * (1.f / 65536.f);
        float var = S2 * (1.f / 65536.f) - mu * mu;
        float al = gw[img & 63] * rsqrtf(var + 1e-5f);
        A[img] = al;
        B[img] = gb[img & 63] - mu * al;
    }
}

__global__ void k_cnapply(const float* __restrict__ X, const float* __restrict__ A,
                          const float* __restrict__ B, float* __restrict__ Y) {
    int gid = blockIdx.x * 256 + threadIdx.x;
    int img = gid >> 14;
    float a = A[img], b = B[img];
    float4 v = ((const float4*)X)[gid];
    float4 o = {fmaf(a, v.x, b), fmaf(a, v.y, b), fmaf(a, v.z, b), fmaf(a, v.w, b)};
    ((float4*)Y)[gid] = o;
}

// ---------------- EMA helpers -----------------------------------------------
__global__ void k_rowmean(const float* __restrict__ Y, float* __restrict__ XH) {
    int row = blockIdx.x * 4 + (threadIdx.x >> 6);
    int lane = threadIdx.x & 63;
    float4 v = ((const float4*)(Y + (size_t)row * 256))[lane];
    float s = v.x + v.y + v.z + v.w;
    for (int o = 32; o; o >>= 1) s += __shfl_down(s, o);
    if (lane == 0) XH[row] = s * (1.f / 256.f);
}

__global__ void k_colmean(const float* __restrict__ Y, float* __restrict__ XW) {
    int gid = blockIdx.x * 256 + threadIdx.x;
    int img = gid >> 8, w = gid & 255;
    const float* p = Y + (size_t)img * 65536 + w;
    float s = 0.f;
    for (int h = 0; h < 256; h++) s += p[h * 256];
    XW[gid] = s * (1.f / 256.f);
}

__global__ void k_hw1x1(const float* __restrict__ XH, const float* __restrict__ XW,
                        const float* __restrict__ W1, const float* __restrict__ B1,
                        float* __restrict__ SH, float* __restrict__ SW) {
    int gid = blockIdx.x * 256 + threadIdx.x;
    int half = gid >> 16;
    int rem = gid & 65535;
    int bg = rem >> 11, r2 = rem & 2047, co = r2 >> 8, p = r2 & 255;
    const float* src = (half ? XW : XH) + bg * 2048 + p;
    float s = B1[co];
#pragma unroll
    for (int ci = 0; ci < 8; ci++) s = fmaf(W1[co * 8 + ci], src[ci * 256], s);
    float sig = 1.f / (1.f + expf(-s));
    (half ? SW : SH)[bg * 2048 + co * 256 + p] = sig;
}

__global__ __launch_bounds__(256) void k_emastats(const float* __restrict__ Y,
                                                  const float* __restrict__ SH,
                                                  const float* __restrict__ SW,
                                                  const float* __restrict__ gnw,
                                                  const float* __restrict__ gnb,
                                                  float* __restrict__ A, float* __restrict__ B) {
    __shared__ float s1b[4], s2b[4];
    const int img = blockIdx.x;
    const int bg = img >> 3, ci = img & 7;
    const float* base = Y + (size_t)img * 65536;
    const float* sh = SH + bg * 2048 + ci * 256;
    const float* sw = SW + bg * 2048 + ci * 256;
    const int tid = threadIdx.x, lane = tid & 63, wid = tid >> 6;
    float s = 0.f, s2 = 0.f;
    for (int i = tid; i < 65536; i += 256) {
        int h = i >> 8, w = i & 255;
        float t = base[i] * sh[h] * sw[w];
        s += t;
        s2 += t * t;
    }
    for (int o = 32; o; o >>= 1) { s += __shfl_down(s, o); s2 += __shfl_down(s2, o); }
    if (lane == 0) { s1b[wid] = s; s2b[wid] = s2; }
    __syncthreads();
    if (tid == 0) {
        float S = s1b[0] + s1b[1] + s1b[2] + s1b[3];
        float S2 = s2b[0] + s2b[1] + s2b[2] + s2b[3];
        float mu = S * (1.f / 65536.f);
        float var = S2 * (1.f / 65536.f) - mu * mu;
        float al = gnw[ci] * rsqrtf(var + 1e-5f);
        A[img] = al;
        B[img] = gnb[ci] - mu * al;
    }
}

__global__ void k_ema_smalls(const float* __restrict__ X2S, const float* __restrict__ EA,
                             const float* __restrict__ EB, const float* __restrict__ gnb,
                             float* __restrict__ Q, float* __restrict__ R,
                             float* __restrict__ P11) {
    int tid = threadIdx.x;
    int ci = tid & 7;
    float m2 = X2S[tid] * (1.f / 65536.f);
    float mx = m2;
    mx = fmaxf(mx, __shfl_xor(mx, 1, 8));
    mx = fmaxf(mx, __shfl_xor(mx, 2, 8));
    mx = fmaxf(mx, __shfl_xor(mx, 4, 8));
    float e = expf(m2 - mx);
    float se = e;
    se += __shfl_xor(se, 1, 8); se += __shfl_xor(se, 2, 8); se += __shfl_xor(se, 4, 8);
    float x21 = e / se;
    Q[tid] = x21 * EA[tid];
    float rt = x21 * EB[tid];
    rt += __shfl_xor(rt, 1, 8); rt += __shfl_xor(rt, 2, 8); rt += __shfl_xor(rt, 4, 8);
    if (ci == 0) R[tid >> 3] = rt;
    float g = gnb[ci];
    float gm = g;
    gm = fmaxf(gm, __shfl_xor(gm, 1, 8));
    gm = fmaxf(gm, __shfl_xor(gm, 2, 8));
    gm = fmaxf(gm, __shfl_xor(gm, 4, 8));
    float ge = expf(g - gm);
    float gs = ge;
    gs += __shfl_xor(gs, 1, 8); gs += __shfl_xor(gs, 2, 8); gs += __shfl_xor(gs, 4, 8);
    if (tid < 8) P11[tid] = ge / gs;
}

// NOTE: X2 and Out intentionally NOT __restrict__ — they alias (both d_out).
__global__ __launch_bounds__(256) void k_ema_final(const float* __restrict__ Y,
                                                   const float* X2,
                                                   const float* __restrict__ SH,
                                                   const float* __restrict__ SW,
                                                   const float* __restrict__ P11,
                                                   const float* __restrict__ Q,
                                                   const float* __restrict__ R,
                                                   float* Out) {
    int gid = blockIdx.x * 256 + threadIdx.x;
    int bg = gid >> 14, rem = gid & 16383;
    int h = rem >> 6, w4i = rem & 63;
    float4 ys[8];
    float rv = R[bg];
    float4 acc = {rv, rv, rv, rv};
#pragma unroll
    for (int ci = 0; ci < 8; ci++) {
        size_t base = ((size_t)(bg * 8 + ci)) * 65536 + (size_t)h * 256;
        float4 yv = ((const float4*)(Y + base))[w4i];
        float4 xv = ((const float4*)(X2 + base))[w4i];
        ys[ci] = yv;
        float p = P11[ci], q = Q[bg * 8 + ci];
        float shv = SH[bg * 2048 + ci * 256 + h];
        float4 swv = ((const float4*)(SW + bg * 2048 + ci * 256))[w4i];
        float qs = q * shv;
        acc.x += p * xv.x + qs * yv.x * swv.x;
        acc.y += p * xv.y + qs * yv.y * swv.y;
        acc.z += p * xv.z + qs * yv.z * swv.z;
        acc.w += p * xv.w + qs * yv.w * swv.w;
    }
    float4 sg;
    sg.x = 1.f / (1.f + expf(-acc.x));
    sg.y = 1.f / (1.f + expf(-acc.y));
    sg.z = 1.f / (1.f + expf(-acc.z));
    sg.w = 1.f / (1.f + expf(-acc.w));
#pragma unroll
    for (int ci = 0; ci < 8; ci++) {
        float4 o = {ys[ci].x * sg.x, ys[ci].y * sg.y, ys[ci].z * sg.z, ys[ci].w * sg.w};
        ((float4*)(Out + ((size_t)(bg * 8 + ci)) * 65536 + (size_t)h * 256))[w4i] = o;
    }
}

// ---------------- launch ----------------------------------------------------
extern "C" void kernel_launch(void* const* d_in, const int* in_sizes, int n_in,
                              void* d_out, int out_size, void* d_ws, size_t ws_size,
                              hipStream_t stream) {
    (void)in_sizes; (void)n_in; (void)out_size; (void)ws_size;
    const float* x     = (const float*)d_in[0];
    const float* thr   = (const float*)d_in[1];
    const float* w_c1  = (const float*)d_in[2];
    const float* w_c2  = (const float*)d_in[3];
    const float* w_out = (const float*)d_in[4];
    const float* b_out = (const float*)d_in[5];
    const float* gn_w  = (const float*)d_in[6];
    const float* gn_b  = (const float*)d_in[7];
    const float* ew1   = (const float*)d_in[8];
    const float* eb1   = (const float*)d_in[9];
    const float* ew3   = (const float*)d_in[10];
    const float* eb3   = (const float*)d_in[11];
    const float* egw   = (const float*)d_in[12];
    const float* egb   = (const float*)d_in[13];

    float* ws   = (float*)d_ws;
    float* C256 = ws + OFF_C256;   // rows 0..63 are E = C64
    float* C128 = ws + OFF_C128;
    float* GATE = ws + OFF_GATE;
    float* SA_A = ws + OFF_STATA;
    float* SA_B = ws + OFF_STATB;
    float* EMAA = ws + OFF_EMAA;
    float* EMAB = ws + OFF_EMAB;
    float* X2S  = ws + OFF_X2SUM;
    float* Qb   = ws + OFF_Q;
    float* Rb   = ws + OFF_R;
    float* P11b = ws + OFF_P11;
    float* XH   = ws + OFF_XH;
    float* XW   = ws + OFF_XW;
    float* SHp  = ws + OFF_SH;
    float* SWp  = ws + OFF_SW;
    float* BIG  = ws + OFF_BIG;

    float* DO  = (float*)d_out;
    float* Ubuf = DO;               // 64x256 x 256 imgs = 4,194,304
    float* Vbuf = DO + 4194304;     // 64x64  x 256 imgs = 1,048,576
    float* Wbuf = DO + 5242880;     // 256x64 x 256 imgs = 4,194,304
    float* LLb = DO;                // spatial chain reuses DO after channel done
    float* T1  = DO + 4194304;
    float* T2  = DO + 8388608;

    k_dctmat<<<320, 256, 0, stream>>>(C256, C128);

    // ---- channel branch: dct_ = x - E^T((E x)E^T)E  (rank-64) ----
    k_bgemm<64, 256, 256, 256, 256, false, false, 0, 65536, 0>
        <<<dim3(4, 1, 256), 256, 0, stream>>>(C256, x, Ubuf, nullptr);
    k_bgemm<64, 64, 256, 256, 256, false, true, 16384, 0, 0>
        <<<dim3(1, 1, 256), 256, 0, stream>>>(Ubuf, C256, Vbuf, nullptr);
    k_bgemm<256, 64, 64, 256, 64, true, false, 0, 4096, 0>
        <<<dim3(1, 4, 256), 256, 0, stream>>>(C256, Vbuf, Wbuf, nullptr);
    k_bgemm<256, 256, 64, 64, 256, false, false, 16384, 0, 3>
        <<<dim3(4, 4, 256), 256, 0, stream>>>(Wbuf, C256, BIG, x);
    k_pool_gate<<<256, 256, 0, stream>>>(BIG, w_c1, w_c2, GATE);

    // ---- spatial branch (inside DO) ----
    k_ll<<<16384, 256, 0, stream>>>(x, LLb);
    k_gemm<128, true, 0><<<dim3(2, 2, 256), 256, 0, stream>>>(C128, LLb, T1, nullptr);
    k_gemm<128, false, 1><<<dim3(2, 2, 256), 256, 0, stream>>>(C128, T1, T2, thr);
    k_gemm<128, true, 0><<<dim3(2, 2, 256), 256, 0, stream>>>(C128, T2, T1, nullptr);
    k_gemm<128, false, 0><<<dim3(2, 2, 256), 256, 0, stream>>>(C128, T1, T2, nullptr);

    // ---- fuse: z = x * (up2(d2) + gate) -> BIG ----
    k_zassm<<<16384, 256, 0, stream>>>(x, T2, GATE, BIG);

    // ---- conv 64->64 + relu -> DO ; channel_norm -> y in BIG ----
    k_conv3<64, true, false><<<dim3(8, 8, 32), 256, 0, stream>>>(BIG, w_out, b_out, DO, nullptr);
    k_cnstats<<<256, 256, 0, stream>>>(DO, gn_w, gn_b, SA_A, SA_B);
    k_cnapply<<<16384, 256, 0, stream>>>(DO, SA_A, SA_B, BIG);

    // ---- EMA ----
    k_rowmean<<<16384, 256, 0, stream>>>(BIG, XH);
    k_colmean<<<256, 256, 0, stream>>>(BIG, XW);
    k_hw1x1<<<512, 256, 0, stream>>>(XH, XW, ew1, eb1, SHp, SWp);
    k_emastats<<<256, 256, 0, stream>>>(BIG, SHp, SWp, egw, egb, EMAA, EMAB);
    hipMemsetAsync(X2S, 0, 256 * sizeof(float), stream);
    k_conv3<8, false, true><<<dim3(8, 8, 32), 256, 0, stream>>>(BIG, ew3, eb3, DO, X2S);
    k_ema_smalls<<<1, 256, 0, stream>>>(X2S, EMAA, EMAB, egb, Qb, Rb, P11b);
    k_ema_final<<<2048, 256, 0, stream>>>(BIG, DO, SHp, SWp, P11b, Qb, Rb, (float*)d_out);
}